// Round 4
// baseline (431.854 us; speedup 1.0000x reference)
//
#include <hip/hip_runtime.h>

#define SEQ   200
#define BATCH 4096
#define EMB   100
#define HID   300
#define NH1   256
#define BM    16
#define NHFR  10             // h frags: h cols k=0..299 (pad to 320)
#define NXFR  4              // xe frags: k=0..99 (pad to 128)
#define FB    1024           // bytes per frag block (32 k x 16 rows x 2B)
#define HBUF  (NHFR * FB)    // one h buffer (10 KB), double-buffered
#define XBUF  (NXFR * FB)    // one xe slot (4 KB), triple-buffered
#define NTMAX 3
#define NHF   10
#define H1P   260

typedef _Float16 half8 __attribute__((ext_vector_type(8)));
typedef _Float16 half4h __attribute__((ext_vector_type(4)));
typedef float floatx4 __attribute__((ext_vector_type(4)));

__device__ __forceinline__ float fast_tanh(float x) {
    float e = __expf(2.0f * x);
    float r = __builtin_amdgcn_rcpf(e + 1.0f);
    return 1.0f - 2.0f * r;
}

// frag-space byte offset of (batch row m, k)
__device__ __forceinline__ int fragoff(int m, int k) {
    return (k >> 5) * FB + ((k >> 3) & 3) * 256 + m * 16 + (k & 7) * 2;
}

// Per timestep t:
//   1. issue 10 h-frag ds_reads from buf p  (h(t-1), published by last barrier)
//   2. stager: store pf (= xe(t+2)) into xe slot (t+2)%3; gather xe(t+3) -> pf
//   3. h-MFMA chain, 10 deep, C = accn (bias + xe(t)*W_ih, computed last step)
//   4. issue 4 xe-frag ds_reads from slot (t+1)%3 (published one barrier ago)
//   5. tanh + h stores into buf 1-p
//   6. accn = bias + xe(t+1)*W_ih  (4 MFMAs/tile, fills the pre-barrier shadow)
//   7. lgkmcnt(0)-only barrier (vmcnt NOT drained; gather rides through)
#define T_LOOP(NTT)                                                                   \
    _Pragma("unroll 2")                                                               \
    for (int t = 0; t < SEQ; ++t) {                                                   \
        const int p = t & 1;                                                          \
        const char* rbh = ubh + p * HBUF + rdo;                                       \
        char*       wbh = ubh + (1 - p) * HBUF;                                       \
        half8 afh[NHFR];                                                              \
        _Pragma("unroll")                                                             \
        for (int kk = 0; kk < NHFR; ++kk) afh[kk] = *(const half8*)(rbh + kk * FB);   \
        if (is_st && (t + 2 < SEQ)) {                                                 \
            half4h hv; hv[0] = (_Float16)pf.x; hv[1] = (_Float16)pf.y;                \
                       hv[2] = (_Float16)pf.z; hv[3] = (_Float16)pf.w;                \
            *(half4h*)(ubx + sw + xwo) = hv;                                          \
        }                                                                             \
        if (is_st && (t + 3 < SEQ)) {                                                 \
            const int idx = xs[(t + 3) * BM + gr];                                    \
            pf = ((const float4*)emb)[idx * 25 + gc];                                 \
        }                                                                             \
        floatx4 acc[NTT];                                                             \
        _Pragma("unroll")                                                             \
        for (int tt = 0; tt < NTT; ++tt) acc[tt] = accn[tt];                          \
        _Pragma("unroll")                                                             \
        for (int kk = 0; kk < NHFR; ++kk) {                                           \
            _Pragma("unroll")                                                         \
            for (int tt = 0; tt < NTT; ++tt)                                          \
                acc[tt] = __builtin_amdgcn_mfma_f32_16x16x32_f16(Wh[tt][kk], afh[kk], \
                                                                 acc[tt], 0, 0, 0);   \
        }                                                                             \
        half8 afx[NXFR];                                                              \
        if (t + 1 < SEQ) {                                                            \
            _Pragma("unroll")                                                         \
            for (int kk = 0; kk < NXFR; ++kk)                                         \
                afx[kk] = *(const half8*)(ubx + sr + rdo + kk * FB);                  \
        }                                                                             \
        _Pragma("unroll")                                                             \
        for (int tt = 0; tt < NTT; ++tt) {                                            \
            half4h hv;                                                                \
            _Pragma("unroll")                                                         \
            for (int r = 0; r < 4; ++r) hv[r] = (_Float16)fast_tanh(acc[tt][r]);      \
            *(half4h*)(wbh + hwo[tt]) = hv;                                           \
        }                                                                             \
        if (t + 1 < SEQ) {                                                            \
            _Pragma("unroll")                                                         \
            for (int tt = 0; tt < NTT; ++tt) {                                        \
                accn[tt] = biasv[tt];                                                 \
                _Pragma("unroll")                                                     \
                for (int kk = 0; kk < NXFR; ++kk)                                     \
                    accn[tt] = __builtin_amdgcn_mfma_f32_16x16x32_f16(Wx[tt][kk],     \
                                                      afx[kk], accn[tt], 0, 0, 0);    \
            }                                                                         \
        }                                                                             \
        sw += XBUF; if (sw >= 3 * XBUF) sw = 0;                                       \
        sr += XBUF; if (sr >= 3 * XBUF) sr = 0;                                       \
        asm volatile("s_waitcnt lgkmcnt(0)" ::: "memory");                            \
        __builtin_amdgcn_s_barrier();                                                 \
    }

__global__ void __launch_bounds__(512)
rnn_fused(const int* __restrict__ x, const float* __restrict__ emb,
          const float* __restrict__ W_ih, const float* __restrict__ b_ih,
          const float* __restrict__ W_hh, const float* __restrict__ b_hh,
          const float* __restrict__ W1, const float* __restrict__ b1,
          const float* __restrict__ W2, const float* __restrict__ b2,
          float* __restrict__ out)
{
    __shared__ __align__(16) _Float16 ufh[2][NHFR][512];  // h, double-buffered (20 KB)
    __shared__ __align__(16) _Float16 ufx[3][NXFR][512];  // xe, triple-buffered (12 KB)
    __shared__ int   xs[SEQ * BM];
    __shared__ float h1s[BM][H1P];

    const int tid  = threadIdx.x;
    const int lane = tid & 63;
    const int w    = tid >> 6;
    const int ln15 = lane & 15;
    const int q    = lane >> 4;
    const int row0 = blockIdx.x * BM;

    // 19 tiles of 16 cols: waves 0-2 get 3, waves 3-7 get 2
    const int t0 = (w < 3) ? 3 * w : 2 * w + 3;

    for (int i = tid; i < 2 * NHFR * 512 / 2; i += 512) ((unsigned int*)ufh)[i] = 0u;
    for (int i = tid; i < 3 * NXFR * 512 / 2; i += 512) ((unsigned int*)ufx)[i] = 0u;
    for (int i = tid; i < SEQ * BM; i += 512)
        xs[i] = x[(size_t)(i >> 4) * BATCH + row0 + (i & 15)];

    // ---- W resident in registers (A-operand: lane ln15 = row n, k = kk*32+q*8+j)
    half8   Wh[NTMAX][NHFR];   // W_hh, h-part k=0..299
    half8   Wx[NTMAX][NXFR];   // W_ih, xe-part k=0..99
    floatx4 biasv[NTMAX];
#pragma unroll
    for (int tt = 0; tt < NTMAX; ++tt) {
        const int nb = (t0 + tt) * 16;
#pragma unroll
        for (int r = 0; r < 4; ++r) {
            const int col = nb + 4 * q + r;
            biasv[tt][r] = (col < HID) ? (b_ih[col] + b_hh[col]) : 0.0f;
        }
        const int n = nb + ln15;
#pragma unroll
        for (int kk = 0; kk < NHFR; ++kk) {
            union { half8 h; unsigned int d[4]; } cv;
#pragma unroll
            for (int j = 0; j < 8; ++j) {
                const int k = kk * 32 + q * 8 + j;
                cv.h[j] = (_Float16)((n < HID && k < HID) ? W_hh[n * HID + k] : 0.0f);
            }
            asm volatile("" : "+v"(cv.d[0]), "+v"(cv.d[1]), "+v"(cv.d[2]), "+v"(cv.d[3]));
            Wh[tt][kk] = cv.h;
        }
#pragma unroll
        for (int kk = 0; kk < NXFR; ++kk) {
            union { half8 h; unsigned int d[4]; } cv;
#pragma unroll
            for (int j = 0; j < 8; ++j) {
                const int k = kk * 32 + q * 8 + j;
                cv.h[j] = (_Float16)((n < HID && k < EMB) ? W_ih[n * EMB + k] : 0.0f);
            }
            asm volatile("" : "+v"(cv.d[0]), "+v"(cv.d[1]), "+v"(cv.d[2]), "+v"(cv.d[3]));
            Wx[tt][kk] = cv.h;
        }
    }

    // ---- precomputed LDS byte offsets
    char* ubh = (char*)ufh;
    char* ubx = (char*)ufx;
    const int rdo = lane * 16;
    int hwo[NTMAX];
#pragma unroll
    for (int tt = 0; tt < NTMAX; ++tt)
        hwo[tt] = fragoff(ln15, (t0 + tt) * 16 + 4 * q);

    // xe stager: 400 float4 chunks, TRANSPOSED map (gr = tid&15) so a wave's
    // 64 lanes span 16 rows x 4 cols -> ds_write banks 2-way (free), vs the
    // old row-major map whose 25-lane rows hit only 2 banks (~10-way conflict).
    const bool is_st = (tid < 400);
    const int  gr = tid & 15, gc = tid >> 4;
    const int  xwo = fragoff(gr, gc * 4);
    __syncthreads();

    // ---- stage xe(0) -> slot 0, xe(1) -> slot 1
    float4 pf = {0.0f, 0.0f, 0.0f, 0.0f};
    if (is_st) {
        const int i0 = xs[gr];
        const float4 f0 = ((const float4*)emb)[i0 * 25 + gc];
        half4h h0; h0[0] = (_Float16)f0.x; h0[1] = (_Float16)f0.y;
                   h0[2] = (_Float16)f0.z; h0[3] = (_Float16)f0.w;
        *(half4h*)(ubx + xwo) = h0;
        const int i1 = xs[BM + gr];
        const float4 f1 = ((const float4*)emb)[i1 * 25 + gc];
        half4h h1v; h1v[0] = (_Float16)f1.x; h1v[1] = (_Float16)f1.y;
                    h1v[2] = (_Float16)f1.z; h1v[3] = (_Float16)f1.w;
        *(half4h*)(ubx + XBUF + xwo) = h1v;
    }
    __syncthreads();

    // ---- accn(0) = bias + xe(0)*W_ih (slot 0); gather xe(2) -> pf
    floatx4 accn[NTMAX];
    {
        half8 afx0[NXFR];
#pragma unroll
        for (int kk = 0; kk < NXFR; ++kk)
            afx0[kk] = *(const half8*)(ubx + rdo + kk * FB);
#pragma unroll
        for (int tt = 0; tt < NTMAX; ++tt) {
            accn[tt] = biasv[tt];
#pragma unroll
            for (int kk = 0; kk < NXFR; ++kk)
                accn[tt] = __builtin_amdgcn_mfma_f32_16x16x32_f16(Wx[tt][kk], afx0[kk],
                                                                  accn[tt], 0, 0, 0);
        }
    }
    if (is_st) {
        const int i2 = xs[2 * BM + gr];
        pf = ((const float4*)emb)[i2 * 25 + gc];
    }

    int sw = 2 * XBUF;   // write slot (t+2)%3, t=0 -> slot 2
    int sr = XBUF;       // read  slot (t+1)%3, t=0 -> slot 1

    if (w < 3) {
        T_LOOP(3)
    } else {
        T_LOOP(2)
    }

    // ---- head: h1 = relu(h @ W1^T + b1); final h(199) in h-buffer 0
    {
        const int hro = fragoff(ln15, q * 8);
        floatx4 hacc[2];
        int ncol[2];
#pragma unroll
        for (int tt = 0; tt < 2; ++tt) {
            const int n = (w * 2 + tt) * 16 + ln15;
            ncol[tt] = n;
            const float b = b1[n];
            hacc[tt][0] = b; hacc[tt][1] = b; hacc[tt][2] = b; hacc[tt][3] = b;
        }
#pragma unroll
        for (int kk = 0; kk < NHF; ++kk) {
            const half8 a = *(const half8*)(ubh + hro + kk * FB);
#pragma unroll
            for (int tt = 0; tt < 2; ++tt) {
                half8 bv;
#pragma unroll
                for (int j = 0; j < 8; ++j) {
                    const int k = kk * 32 + q * 8 + j;
                    bv[j] = (_Float16)((k < HID) ? W1[ncol[tt] * HID + k] : 0.0f);
                }
                hacc[tt] = __builtin_amdgcn_mfma_f32_16x16x32_f16(bv, a, hacc[tt], 0, 0, 0);
            }
        }
        // D transposed: lane ln15 = batch row, cols (2w+tt)*16 + 4q + r
#pragma unroll
        for (int tt = 0; tt < 2; ++tt) {
            float4 fv;
            fv.x = fmaxf(hacc[tt][0], 0.0f); fv.y = fmaxf(hacc[tt][1], 0.0f);
            fv.z = fmaxf(hacc[tt][2], 0.0f); fv.w = fmaxf(hacc[tt][3], 0.0f);
            *(float4*)&h1s[ln15][(w * 2 + tt) * 16 + 4 * q] = fv;
        }
    }
    __syncthreads();

    // ---- out = h1 @ W2^T + b2: 16 rows x 2 cols
    if (tid < 32) {
        const int r = tid & 15, o = tid >> 4;
        float a = b2[o];
        const float* ww = W2 + (size_t)o * NH1;
        for (int k = 0; k < NH1; ++k) a += h1s[r][k] * ww[k];
        out[(size_t)(row0 + r) * 2 + o] = a;
    }
}

extern "C" void kernel_launch(void* const* d_in, const int* in_sizes, int n_in,
                              void* d_out, int out_size, void* d_ws, size_t ws_size,
                              hipStream_t stream) {
    const int*   x    = (const int*)d_in[0];
    const float* emb  = (const float*)d_in[1];
    const float* W_ih = (const float*)d_in[2];
    const float* b_ih = (const float*)d_in[3];
    const float* W_hh = (const float*)d_in[4];
    const float* b_hh = (const float*)d_in[5];
    const float* W1   = (const float*)d_in[6];
    const float* b1   = (const float*)d_in[7];
    const float* W2   = (const float*)d_in[8];
    const float* b2   = (const float*)d_in[9];
    float* outp = (float*)d_out;

    hipLaunchKernelGGL(rnn_fused, dim3(BATCH / BM), dim3(512), 0, stream,
                       x, emb, W_ih, b_ih, W_hh, b_hh, W1, b1, W2, b2, outp);
}